// Round 7
// baseline (259.532 us; speedup 1.0000x reference)
//
#include <hip/hip_runtime.h>
#include <math.h>

namespace {

typedef float f32x4 __attribute__((ext_vector_type(4)));

constexpr int kPts  = 2 * 256 * 256;   // 131072 points
constexpr int kHid  = 64;
constexpr int kPath = 384;

// ws float-index layout: ru[kPts*4] | V[384] | flag
constexpr size_t kVOff    = (size_t)kPts * 4;
constexpr size_t kFlagOff = kVOff + kPath;
constexpr size_t kNeedBytes = (kFlagOff + 1) * sizeof(float);

// SH / norm constants
constexpr float kY0   = 0.28209479177387814f;
constexpr float kC1   = 0.4886025119029199f;
constexpr float kC2A  = 1.0925484305920792f;
constexpr float kC2B  = 0.31539156525252005f;
constexpr float kC2C  = 0.5462742152960396f;
constexpr float kS4pi = 3.5449077018110318f;
constexpr float kSq3  = 1.7320508075688772f;
constexpr float kN00  = kS4pi / 64.f;
constexpr float kN01  = kSq3 * kS4pi / 64.f;
constexpr float kN10  = kS4pi / 90.50966799187809f;
constexpr float kN11  = kSq3 * kS4pi / 90.50966799187809f;

// ---------------- stage: ru[pt]={r,x,y,z} + V + flag ----------------
__global__ __launch_bounds__(256)
void stage_kernel(const float* __restrict__ dm,
                  const float* __restrict__ W1,
                  const float* __restrict__ b1,
                  const float* __restrict__ W2,
                  f32x4* __restrict__ ru,
                  float* __restrict__ V,
                  unsigned* __restrict__ flag)
{
    const int pt = blockIdx.x * 256 + threadIdx.x;
    float dx = dm[3 * pt], dy = dm[3 * pt + 1], dz = dm[3 * pt + 2];
    float r  = sqrtf(dx * dx + dy * dy + dz * dz);
    float inv = 1.f / fmaxf(r, 1e-12f);
    f32x4 q; q.x = r; q.y = dx * inv; q.z = dy * inv; q.w = dz * inv;
    ru[pt] = q;

    if (blockIdx.x == 0) {
        for (int p = threadIdx.x; p < kPath; p += 256) {
            float acc = 0.f;
            for (int i = 0; i < kHid; ++i)
                acc += fmaxf(W1[i], 0.f) * W2[i * kPath + p];
            V[p] = acc;
        }
        if (threadIdx.x == 0) {
            unsigned f = 1u;
            for (int i = 0; i < kHid; ++i)
                if (b1[i] != 0.f) f = 0u;
            *flag = f;
        }
    }
}

// ---------------- row kernel: block = 4 consecutive output rows (2MB window) ----------------
__global__ __launch_bounds__(1024)
void row_kernel(const f32x4* __restrict__ ru,
                const float* __restrict__ V,
                const float* __restrict__ b2,
                const float* __restrict__ Q00,
                const float* __restrict__ Q01,
                const float* __restrict__ Q10,
                const float* __restrict__ Q11,
                const unsigned* __restrict__ flag,
                float* __restrict__ out)
{
    if (*flag == 0u) return;   // general path handled by mono_pred
    const int tid = threadIdx.x;

    // per-row uniforms: val = p0*wx + (a.Y1)*wy + (b.Y2)*wz, w* = fma(r, v*, c*)
    float P0[4], A0[4], A1[4], A2[4], B0[4], B1[4], B2v[4], B3[4], B4[4];
    float VX[4], CX[4], VY[4], CY[4], VZ[4], CZ[4];
#pragma unroll
    for (int j = 0; j < 4; ++j) {
        const int row = blockIdx.x * 4 + j;
        const int rA = row >> 5, rB = row & 31;
        float p0=0, a0=0, a1=0, a2=0, b0=0, b1v=0, b2c=0, b3=0, b4=0;
        float vx=0, cx=0, vy=0, cy=0, vz=0, cz=0;
        if (rA < 8) {
            const int u = rA;
            if (rB < 8) {
                const int uv = u * 8 + rB;
                p0 = kN00 * Q00[0] * kY0;
                vx = V[uv]; cx = b2[uv];
            } else {
                const int v = (rB - 8) / 3, jc = (rB - 8) % 3, uv = u * 8 + v;
                a0 = kN01 * kC1 * Q01[jc * 3 + 0];
                a1 = kN01 * kC1 * Q01[jc * 3 + 1];
                a2 = kN01 * kC1 * Q01[jc * 3 + 2];
                vy = V[64 + uv]; cy = b2[64 + uv];
            }
        } else {
            const int t = rA - 8, u = t / 3, ir = t % 3;
            if (rB < 8) {
                const int uv = u * 8 + rB;
                a0 = kN10 * kC1 * Q10[ir * 3 + 0];
                a1 = kN10 * kC1 * Q10[ir * 3 + 1];
                a2 = kN10 * kC1 * Q10[ir * 3 + 2];
                vy = V[128 + uv]; cy = b2[128 + uv];
            } else {
                const int v = (rB - 8) / 3, jc = (rB - 8) % 3;
                const int e = ir * 3 + jc, uv = u * 8 + v;
                const float* q = Q11 + e * 9;
                p0 = kN11 * kY0 * q[0];
                vx = V[192 + 3 * uv]; cx = b2[192 + 3 * uv];
                a0 = kN11 * kC1 * q[1];
                a1 = kN11 * kC1 * q[2];
                a2 = kN11 * kC1 * q[3];
                vy = V[193 + 3 * uv]; cy = b2[193 + 3 * uv];
                b0  = kN11 * kC2A * q[4];
                b1v = kN11 * kC2A * q[5];
                b2c = kN11 * kC2B * q[6];
                b3  = kN11 * kC2A * q[7];
                b4  = kN11 * kC2C * q[8];
                vz = V[194 + 3 * uv]; cz = b2[194 + 3 * uv];
            }
        }
        P0[j]=p0; A0[j]=a0; A1[j]=a1; A2[j]=a2;
        B0[j]=b0; B1[j]=b1v; B2v[j]=b2c; B3[j]=b3; B4[j]=b4;
        VX[j]=vx; CX[j]=cx; VY[j]=vy; CY[j]=cy; VZ[j]=vz; CZ[j]=cz;
    }

    const size_t rowbase = (size_t)blockIdx.x * 4 * kPts;

#pragma unroll 1
    for (int c = 0; c < kPts / 4096; ++c) {
        const int pt0 = c * 4096 + tid * 4;
        f32x4 q0 = ru[pt0], q1 = ru[pt0 + 1], q2 = ru[pt0 + 2], q3 = ru[pt0 + 3];
        float R[4] = { q0.x, q1.x, q2.x, q3.x };
        float X[4] = { q0.y, q1.y, q2.y, q3.y };
        float Y[4] = { q0.z, q1.z, q2.z, q3.z };
        float Z[4] = { q0.w, q1.w, q2.w, q3.w };
        float XY[4], YZ[4], ZZ[4], XZ[4], XXYY[4];
#pragma unroll
        for (int k = 0; k < 4; ++k) {
            XY[k] = X[k] * Y[k];
            YZ[k] = Y[k] * Z[k];
            ZZ[k] = fmaf(3.f * Z[k], Z[k], -1.f);
            XZ[k] = X[k] * Z[k];
            XXYY[k] = fmaf(X[k], X[k], -(Y[k] * Y[k]));
        }
#pragma unroll
        for (int j = 0; j < 4; ++j) {
            f32x4 o;
#pragma unroll
            for (int k = 0; k < 4; ++k) {
                float wx = fmaf(R[k], VX[j], CX[j]);
                float wy = fmaf(R[k], VY[j], CY[j]);
                float wz = fmaf(R[k], VZ[j], CZ[j]);
                float lin = fmaf(A2[j], X[k], fmaf(A1[j], Z[k], A0[j] * Y[k]));
                float quad = fmaf(B0[j], XY[k],
                             fmaf(B1[j], YZ[k],
                             fmaf(B2v[j], ZZ[k],
                             fmaf(B3[j], XZ[k], B4[j] * XXYY[k]))));
                o[k] = fmaf(P0[j], wx, fmaf(lin, wy, quad * wz));
            }
            *reinterpret_cast<f32x4*>(out + rowbase + (size_t)j * kPts + pt0) = o;
        }
    }
}

// ---------------- general-path monolith (predicated or standalone) ----------------
template <bool PRED>
__global__ __launch_bounds__(256)
void mono_kernel(const float* __restrict__ dm,
                 const float* __restrict__ W1,
                 const float* __restrict__ b1,
                 const float* __restrict__ W2,
                 const float* __restrict__ b2,
                 const float* __restrict__ Q00,
                 const float* __restrict__ Q01,
                 const float* __restrict__ Q10,
                 const float* __restrict__ Q11,
                 const unsigned* __restrict__ flag,
                 float* __restrict__ out)
{
    if constexpr (PRED) { if (*flag != 0u) return; }  // fast path handled by row_kernel
    const int g   = blockIdx.x * blockDim.x + threadIdx.x;  // 4 points
    const int uv0 = blockIdx.y * 8;

    const f32x4* dmv = reinterpret_cast<const f32x4*>(dm) + 3 * (size_t)g;
    f32x4 f0 = dmv[0], f1 = dmv[1], f2 = dmv[2];
    float px[4] = { f0.x, f0.w, f1.z, f2.y };
    float py[4] = { f0.y, f1.x, f1.w, f2.z };
    float pz[4] = { f0.z, f1.y, f2.x, f2.w };

    float r[4], ux[4], uy[4], uz[4];
#pragma unroll
    for (int p = 0; p < 4; ++p) {
        r[p] = sqrtf(px[p]*px[p] + py[p]*py[p] + pz[p]*pz[p]);
        float inv = 1.0f / fmaxf(r[p], 1e-12f);
        ux[p] = px[p]*inv; uy[p] = py[p]*inv; uz[p] = pz[p]*inv;
    }
    float Y10[4], Y11v[4], Y12[4], Y2[5][4];
#pragma unroll
    for (int p = 0; p < 4; ++p) {
        Y10[p] = kC1 * uy[p]; Y11v[p] = kC1 * uz[p]; Y12[p] = kC1 * ux[p];
        Y2[0][p] = kC2A * ux[p] * uy[p];
        Y2[1][p] = kC2A * uy[p] * uz[p];
        Y2[2][p] = kC2B * (3.f * uz[p] * uz[p] - 1.f);
        Y2[3][p] = kC2A * ux[p] * uz[p];
        Y2[4][p] = kC2C * (ux[p]*ux[p] - uy[p]*uy[p]);
    }
    const float s00 = kN00 * Q00[0] * kY0;
    float G0[9];
#pragma unroll
    for (int e = 0; e < 9; ++e) G0[e] = kN11 * Q11[e*9] * kY0;
    float g01[3][4], g10[3][4], G1[9][4], G2[9][4];
#pragma unroll
    for (int jc = 0; jc < 3; ++jc)
#pragma unroll
        for (int p = 0; p < 4; ++p)
            g01[jc][p] = kN01 * (Q01[jc*3]*Y10[p] + Q01[jc*3+1]*Y11v[p] + Q01[jc*3+2]*Y12[p]);
#pragma unroll
    for (int ir = 0; ir < 3; ++ir)
#pragma unroll
        for (int p = 0; p < 4; ++p)
            g10[ir][p] = kN10 * (Q10[ir*3]*Y10[p] + Q10[ir*3+1]*Y11v[p] + Q10[ir*3+2]*Y12[p]);
#pragma unroll
    for (int e = 0; e < 9; ++e) {
        const float* q = Q11 + e * 9;
#pragma unroll
        for (int p = 0; p < 4; ++p) {
            G1[e][p] = kN11 * (q[1]*Y10[p] + q[2]*Y11v[p] + q[3]*Y12[p]);
            G2[e][p] = kN11 * (q[4]*Y2[0][p] + q[5]*Y2[1][p] + q[6]*Y2[2][p] +
                               q[7]*Y2[3][p] + q[8]*Y2[4][p]);
        }
    }
    float* __restrict__ obase = out + 4 * (size_t)g;
    auto stf = [&](int row, const float* v4) {
        f32x4 q; q.x=v4[0]; q.y=v4[1]; q.z=v4[2]; q.w=v4[3];
        *reinterpret_cast<f32x4*>(obase + (size_t)row * kPts) = q;
    };
#pragma unroll 1
    for (int t = 0; t < 8; ++t) {
        const int uv = uv0 + t;
        float a00[4], a01v[4], a10v[4], a110[4], a111[4], a112[4];
#pragma unroll
        for (int p = 0; p < 4; ++p) {
            a00[p]=b2[uv]; a01v[p]=b2[64+uv]; a10v[p]=b2[128+uv];
            a110[p]=b2[192+3*uv]; a111[p]=b2[193+3*uv]; a112[p]=b2[194+3*uv];
        }
#pragma unroll 1
        for (int i = 0; i < kHid; ++i) {
            float w1i = W1[i], b1i = b1[i];
            const float* row = W2 + (size_t)i * kPath;
            float c00=row[uv], c01=row[64+uv], c10=row[128+uv];
            float c50=row[192+3*uv], c51=row[193+3*uv], c52=row[194+3*uv];
#pragma unroll
            for (int p = 0; p < 4; ++p) {
                float hi = fmaxf(fmaf(r[p], w1i, b1i), 0.f);
                a00[p]=fmaf(hi,c00,a00[p]); a01v[p]=fmaf(hi,c01,a01v[p]);
                a10v[p]=fmaf(hi,c10,a10v[p]); a110[p]=fmaf(hi,c50,a110[p]);
                a111[p]=fmaf(hi,c51,a111[p]); a112[p]=fmaf(hi,c52,a112[p]);
            }
        }
        const int u = uv >> 3, v = uv & 7;
        const int rowu = u * 32;
        float tmp[4];
#pragma unroll
        for (int p = 0; p < 4; ++p) tmp[p] = s00 * a00[p];
        stf(rowu + v, tmp);
#pragma unroll
        for (int jc = 0; jc < 3; ++jc) {
#pragma unroll
            for (int p = 0; p < 4; ++p) tmp[p] = g01[jc][p] * a01v[p];
            stf(rowu + 8 + v*3 + jc, tmp);
        }
#pragma unroll
        for (int ir = 0; ir < 3; ++ir) {
            const int rowb = (8 + u*3 + ir) * 32;
#pragma unroll
            for (int p = 0; p < 4; ++p) tmp[p] = g10[ir][p] * a10v[p];
            stf(rowb + v, tmp);
#pragma unroll
            for (int jc = 0; jc < 3; ++jc) {
                const int e = ir*3 + jc;
#pragma unroll
                for (int p = 0; p < 4; ++p)
                    tmp[p] = fmaf(G0[e], a110[p], fmaf(G1[e][p], a111[p], G2[e][p]*a112[p]));
                stf(rowb + 8 + v*3 + jc, tmp);
            }
        }
    }
}

} // namespace

extern "C" void kernel_launch(void* const* d_in, const int* in_sizes, int n_in,
                              void* d_out, int out_size, void* d_ws, size_t ws_size,
                              hipStream_t stream)
{
    const float* dm  = (const float*)d_in[0];
    const float* W1  = (const float*)d_in[1];
    const float* b1  = (const float*)d_in[2];
    const float* W2  = (const float*)d_in[3];
    const float* b2  = (const float*)d_in[4];
    const float* Q00 = (const float*)d_in[5];
    const float* Q01 = (const float*)d_in[6];
    const float* Q10 = (const float*)d_in[7];
    const float* Q11 = (const float*)d_in[8];
    float* out = (float*)d_out;

    if (ws_size >= kNeedBytes) {
        float*    ws   = (float*)d_ws;
        f32x4*    ru   = (f32x4*)ws;
        float*    V    = ws + kVOff;
        unsigned* flag = (unsigned*)(ws + kFlagOff);
        stage_kernel<<<kPts / 256, 256, 0, stream>>>(dm, W1, b1, W2, ru, V, flag);
        mono_kernel<true><<<dim3(kPts / 4 / 256, 8), 256, 0, stream>>>(
            dm, W1, b1, W2, b2, Q00, Q01, Q10, Q11, flag, out);
        row_kernel<<<256, 1024, 0, stream>>>(
            ru, V, b2, Q00, Q01, Q10, Q11, flag, out);
    } else {
        mono_kernel<false><<<dim3(kPts / 4 / 256, 8), 256, 0, stream>>>(
            dm, W1, b1, W2, b2, Q00, Q01, Q10, Q11, nullptr, out);
    }
}

// Round 8
// 126.412 us; speedup vs baseline: 2.0531x; 2.0531x over previous
//
#include <hip/hip_runtime.h>
#include <math.h>

namespace {

typedef float f32x4 __attribute__((ext_vector_type(4)));

constexpr int kPts  = 2 * 256 * 256;   // 131072 points
constexpr int kHid  = 64;
constexpr int kPath = 384;

// ws float-index layout: ru[kPts*4] | V[384] | flag
constexpr size_t kVOff    = (size_t)kPts * 4;
constexpr size_t kFlagOff = kVOff + kPath;
constexpr size_t kNeedBytes = (kFlagOff + 1) * sizeof(float);

// SH / norm constants
constexpr float kY0   = 0.28209479177387814f;
constexpr float kC1   = 0.4886025119029199f;
constexpr float kC2A  = 1.0925484305920792f;
constexpr float kC2B  = 0.31539156525252005f;
constexpr float kC2C  = 0.5462742152960396f;
constexpr float kS4pi = 3.5449077018110318f;
constexpr float kSq3  = 1.7320508075688772f;
constexpr float kN00  = kS4pi / 64.f;
constexpr float kN01  = kSq3 * kS4pi / 64.f;
constexpr float kN10  = kS4pi / 90.50966799187809f;
constexpr float kN11  = kSq3 * kS4pi / 90.50966799187809f;

// ---------------- stage: ru[pt]={r,x,y,z} + V + flag ----------------
__global__ __launch_bounds__(256)
void stage_kernel(const float* __restrict__ dm,
                  const float* __restrict__ W1,
                  const float* __restrict__ b1,
                  const float* __restrict__ W2,
                  f32x4* __restrict__ ru,
                  float* __restrict__ V,
                  unsigned* __restrict__ flag)
{
    const int pt = blockIdx.x * 256 + threadIdx.x;
    float dx = dm[3 * pt], dy = dm[3 * pt + 1], dz = dm[3 * pt + 2];
    float r  = sqrtf(dx * dx + dy * dy + dz * dz);
    float inv = 1.f / fmaxf(r, 1e-12f);
    f32x4 q; q.x = r; q.y = dx * inv; q.z = dy * inv; q.w = dz * inv;
    ru[pt] = q;

    if (blockIdx.x == 0) {
        for (int p = threadIdx.x; p < kPath; p += 256) {
            float acc = 0.f;
            for (int i = 0; i < kHid; ++i)
                acc += fmaxf(W1[i], 0.f) * W2[i * kPath + p];
            V[p] = acc;
        }
        if (threadIdx.x == 0) {
            unsigned f = 1u;
            for (int i = 0; i < kHid; ++i)
                if (b1[i] != 0.f) f = 0u;
            *flag = f;
        }
    }
}

// ---- row4: block = (4 contiguous rows) x (4096-pt chunk, skewed) ----
__global__ __launch_bounds__(256)
void row4_kernel(const f32x4* __restrict__ ru,
                 const float* __restrict__ V,
                 const float* __restrict__ b2,
                 const float* __restrict__ Q00,
                 const float* __restrict__ Q01,
                 const float* __restrict__ Q10,
                 const float* __restrict__ Q11,
                 const unsigned* __restrict__ flag,
                 float* __restrict__ out)
{
    if (*flag == 0u) return;   // general path handled by predicated mono
    const int tid      = threadIdx.x;
    const int chunkidx = blockIdx.x & 31;
    const int rowgroup = blockIdx.x >> 5;          // 0..255
    const int chunk    = (chunkidx + rowgroup) & 31;   // skew: decorrelate offsets
    const int P0       = chunk * 4096;

    // per-row uniforms: val = p0*wx + (a.Y1)*wy + (b.Y2)*wz, w* = fma(r, v*, c*)
    float P0c[4], A0[4], A1[4], A2[4], B0[4], B1[4], B2v[4], B3[4], B4[4];
    float VX[4], CX[4], VY[4], CY[4], VZ[4], CZ[4];
#pragma unroll
    for (int j = 0; j < 4; ++j) {
        const int row = rowgroup * 4 + j;
        const int rA = row >> 5, rB = row & 31;
        float p0=0, a0=0, a1=0, a2=0, b0=0, b1v=0, b2c=0, b3=0, b4=0;
        float vx=0, cx=0, vy=0, cy=0, vz=0, cz=0;
        if (rA < 8) {
            const int u = rA;
            if (rB < 8) {
                const int uv = u * 8 + rB;
                p0 = kN00 * Q00[0] * kY0;
                vx = V[uv]; cx = b2[uv];
            } else {
                const int v = (rB - 8) / 3, jc = (rB - 8) % 3, uv = u * 8 + v;
                a0 = kN01 * kC1 * Q01[jc * 3 + 0];
                a1 = kN01 * kC1 * Q01[jc * 3 + 1];
                a2 = kN01 * kC1 * Q01[jc * 3 + 2];
                vy = V[64 + uv]; cy = b2[64 + uv];
            }
        } else {
            const int t = rA - 8, u = t / 3, ir = t % 3;
            if (rB < 8) {
                const int uv = u * 8 + rB;
                a0 = kN10 * kC1 * Q10[ir * 3 + 0];
                a1 = kN10 * kC1 * Q10[ir * 3 + 1];
                a2 = kN10 * kC1 * Q10[ir * 3 + 2];
                vy = V[128 + uv]; cy = b2[128 + uv];
            } else {
                const int v = (rB - 8) / 3, jc = (rB - 8) % 3;
                const int e = ir * 3 + jc, uv = u * 8 + v;
                const float* q = Q11 + e * 9;
                p0 = kN11 * kY0 * q[0];
                vx = V[192 + 3 * uv]; cx = b2[192 + 3 * uv];
                a0 = kN11 * kC1 * q[1];
                a1 = kN11 * kC1 * q[2];
                a2 = kN11 * kC1 * q[3];
                vy = V[193 + 3 * uv]; cy = b2[193 + 3 * uv];
                b0  = kN11 * kC2A * q[4];
                b1v = kN11 * kC2A * q[5];
                b2c = kN11 * kC2B * q[6];
                b3  = kN11 * kC2A * q[7];
                b4  = kN11 * kC2C * q[8];
                vz = V[194 + 3 * uv]; cz = b2[194 + 3 * uv];
            }
        }
        P0c[j]=p0; A0[j]=a0; A1[j]=a1; A2[j]=a2;
        B0[j]=b0; B1[j]=b1v; B2v[j]=b2c; B3[j]=b3; B4[j]=b4;
        VX[j]=vx; CX[j]=cx; VY[j]=vy; CY[j]=cy; VZ[j]=vz; CZ[j]=cz;
    }

    const size_t rowbase = (size_t)rowgroup * 4 * kPts;

    // 4 sub-batches of 1024 points; per sub-batch each thread computes 4 pts
    // and stores one f32x4 per row -> per wave 1KB contiguous per row,
    // continuing linearly across sub-batches (4 linear 16KB streams/block).
#pragma unroll 1
    for (int sb = 0; sb < 4; ++sb) {
        const int pt0 = P0 + (tid << 2) + (sb << 10);
        f32x4 q0 = ru[pt0], q1 = ru[pt0 + 1], q2 = ru[pt0 + 2], q3 = ru[pt0 + 3];
        float R[4] = { q0.x, q1.x, q2.x, q3.x };
        float X[4] = { q0.y, q1.y, q2.y, q3.y };
        float Y[4] = { q0.z, q1.z, q2.z, q3.z };
        float Z[4] = { q0.w, q1.w, q2.w, q3.w };
        float XY[4], YZ[4], ZZ[4], XZ[4], XXYY[4];
#pragma unroll
        for (int k = 0; k < 4; ++k) {
            XY[k] = X[k] * Y[k];
            YZ[k] = Y[k] * Z[k];
            ZZ[k] = fmaf(3.f * Z[k], Z[k], -1.f);
            XZ[k] = X[k] * Z[k];
            XXYY[k] = fmaf(X[k], X[k], -(Y[k] * Y[k]));
        }
#pragma unroll
        for (int j = 0; j < 4; ++j) {
            f32x4 o;
#pragma unroll
            for (int k = 0; k < 4; ++k) {
                float wx = fmaf(R[k], VX[j], CX[j]);
                float wy = fmaf(R[k], VY[j], CY[j]);
                float wz = fmaf(R[k], VZ[j], CZ[j]);
                float lin = fmaf(A2[j], X[k], fmaf(A1[j], Z[k], A0[j] * Y[k]));
                float quad = fmaf(B0[j], XY[k],
                             fmaf(B1[j], YZ[k],
                             fmaf(B2v[j], ZZ[k],
                             fmaf(B3[j], XZ[k], B4[j] * XXYY[k]))));
                o[k] = fmaf(P0c[j], wx, fmaf(lin, wy, quad * wz));
            }
            *reinterpret_cast<f32x4*>(out + rowbase + (size_t)j * kPts + pt0) = o;
        }
    }
}

// ---------------- general-path monolith (predicated or standalone) ----------------
template <bool PRED>
__global__ __launch_bounds__(256)
void mono_kernel(const float* __restrict__ dm,
                 const float* __restrict__ W1,
                 const float* __restrict__ b1,
                 const float* __restrict__ W2,
                 const float* __restrict__ b2,
                 const float* __restrict__ Q00,
                 const float* __restrict__ Q01,
                 const float* __restrict__ Q10,
                 const float* __restrict__ Q11,
                 const unsigned* __restrict__ flag,
                 float* __restrict__ out)
{
    if constexpr (PRED) { if (*flag != 0u) return; }
    const int g   = blockIdx.x * blockDim.x + threadIdx.x;  // 4 points
    const int uv0 = blockIdx.y * 8;

    const f32x4* dmv = reinterpret_cast<const f32x4*>(dm) + 3 * (size_t)g;
    f32x4 f0 = dmv[0], f1 = dmv[1], f2 = dmv[2];
    float px[4] = { f0.x, f0.w, f1.z, f2.y };
    float py[4] = { f0.y, f1.x, f1.w, f2.z };
    float pz[4] = { f0.z, f1.y, f2.x, f2.w };

    float r[4], ux[4], uy[4], uz[4];
#pragma unroll
    for (int p = 0; p < 4; ++p) {
        r[p] = sqrtf(px[p]*px[p] + py[p]*py[p] + pz[p]*pz[p]);
        float inv = 1.0f / fmaxf(r[p], 1e-12f);
        ux[p] = px[p]*inv; uy[p] = py[p]*inv; uz[p] = pz[p]*inv;
    }
    float Y10[4], Y11v[4], Y12[4], Y2[5][4];
#pragma unroll
    for (int p = 0; p < 4; ++p) {
        Y10[p] = kC1 * uy[p]; Y11v[p] = kC1 * uz[p]; Y12[p] = kC1 * ux[p];
        Y2[0][p] = kC2A * ux[p] * uy[p];
        Y2[1][p] = kC2A * uy[p] * uz[p];
        Y2[2][p] = kC2B * (3.f * uz[p] * uz[p] - 1.f);
        Y2[3][p] = kC2A * ux[p] * uz[p];
        Y2[4][p] = kC2C * (ux[p]*ux[p] - uy[p]*uy[p]);
    }
    const float s00 = kN00 * Q00[0] * kY0;
    float G0[9];
#pragma unroll
    for (int e = 0; e < 9; ++e) G0[e] = kN11 * Q11[e*9] * kY0;
    float g01[3][4], g10[3][4], G1[9][4], G2[9][4];
#pragma unroll
    for (int jc = 0; jc < 3; ++jc)
#pragma unroll
        for (int p = 0; p < 4; ++p)
            g01[jc][p] = kN01 * (Q01[jc*3]*Y10[p] + Q01[jc*3+1]*Y11v[p] + Q01[jc*3+2]*Y12[p]);
#pragma unroll
    for (int ir = 0; ir < 3; ++ir)
#pragma unroll
        for (int p = 0; p < 4; ++p)
            g10[ir][p] = kN10 * (Q10[ir*3]*Y10[p] + Q10[ir*3+1]*Y11v[p] + Q10[ir*3+2]*Y12[p]);
#pragma unroll
    for (int e = 0; e < 9; ++e) {
        const float* q = Q11 + e * 9;
#pragma unroll
        for (int p = 0; p < 4; ++p) {
            G1[e][p] = kN11 * (q[1]*Y10[p] + q[2]*Y11v[p] + q[3]*Y12[p]);
            G2[e][p] = kN11 * (q[4]*Y2[0][p] + q[5]*Y2[1][p] + q[6]*Y2[2][p] +
                               q[7]*Y2[3][p] + q[8]*Y2[4][p]);
        }
    }
    float* __restrict__ obase = out + 4 * (size_t)g;
    auto stf = [&](int row, const float* v4) {
        f32x4 q; q.x=v4[0]; q.y=v4[1]; q.z=v4[2]; q.w=v4[3];
        *reinterpret_cast<f32x4*>(obase + (size_t)row * kPts) = q;
    };
#pragma unroll 1
    for (int t = 0; t < 8; ++t) {
        const int uv = uv0 + t;
        float a00[4], a01v[4], a10v[4], a110[4], a111[4], a112[4];
#pragma unroll
        for (int p = 0; p < 4; ++p) {
            a00[p]=b2[uv]; a01v[p]=b2[64+uv]; a10v[p]=b2[128+uv];
            a110[p]=b2[192+3*uv]; a111[p]=b2[193+3*uv]; a112[p]=b2[194+3*uv];
        }
#pragma unroll 1
        for (int i = 0; i < kHid; ++i) {
            float w1i = W1[i], b1i = b1[i];
            const float* row = W2 + (size_t)i * kPath;
            float c00=row[uv], c01=row[64+uv], c10=row[128+uv];
            float c50=row[192+3*uv], c51=row[193+3*uv], c52=row[194+3*uv];
#pragma unroll
            for (int p = 0; p < 4; ++p) {
                float hi = fmaxf(fmaf(r[p], w1i, b1i), 0.f);
                a00[p]=fmaf(hi,c00,a00[p]); a01v[p]=fmaf(hi,c01,a01v[p]);
                a10v[p]=fmaf(hi,c10,a10v[p]); a110[p]=fmaf(hi,c50,a110[p]);
                a111[p]=fmaf(hi,c51,a111[p]); a112[p]=fmaf(hi,c52,a112[p]);
            }
        }
        const int u = uv >> 3, v = uv & 7;
        const int rowu = u * 32;
        float tmp[4];
#pragma unroll
        for (int p = 0; p < 4; ++p) tmp[p] = s00 * a00[p];
        stf(rowu + v, tmp);
#pragma unroll
        for (int jc = 0; jc < 3; ++jc) {
#pragma unroll
            for (int p = 0; p < 4; ++p) tmp[p] = g01[jc][p] * a01v[p];
            stf(rowu + 8 + v*3 + jc, tmp);
        }
#pragma unroll
        for (int ir = 0; ir < 3; ++ir) {
            const int rowb = (8 + u*3 + ir) * 32;
#pragma unroll
            for (int p = 0; p < 4; ++p) tmp[p] = g10[ir][p] * a10v[p];
            stf(rowb + v, tmp);
#pragma unroll
            for (int jc = 0; jc < 3; ++jc) {
                const int e = ir*3 + jc;
#pragma unroll
                for (int p = 0; p < 4; ++p)
                    tmp[p] = fmaf(G0[e], a110[p], fmaf(G1[e][p], a111[p], G2[e][p]*a112[p]));
                stf(rowb + 8 + v*3 + jc, tmp);
            }
        }
    }
}

} // namespace

extern "C" void kernel_launch(void* const* d_in, const int* in_sizes, int n_in,
                              void* d_out, int out_size, void* d_ws, size_t ws_size,
                              hipStream_t stream)
{
    const float* dm  = (const float*)d_in[0];
    const float* W1  = (const float*)d_in[1];
    const float* b1  = (const float*)d_in[2];
    const float* W2  = (const float*)d_in[3];
    const float* b2  = (const float*)d_in[4];
    const float* Q00 = (const float*)d_in[5];
    const float* Q01 = (const float*)d_in[6];
    const float* Q10 = (const float*)d_in[7];
    const float* Q11 = (const float*)d_in[8];
    float* out = (float*)d_out;

    if (ws_size >= kNeedBytes) {
        float*    ws   = (float*)d_ws;
        f32x4*    ru   = (f32x4*)ws;
        float*    V    = ws + kVOff;
        unsigned* flag = (unsigned*)(ws + kFlagOff);
        stage_kernel<<<kPts / 256, 256, 0, stream>>>(dm, W1, b1, W2, ru, V, flag);
        mono_kernel<true><<<dim3(kPts / 4 / 256, 8), 256, 0, stream>>>(
            dm, W1, b1, W2, b2, Q00, Q01, Q10, Q11, flag, out);
        row4_kernel<<<32 * 256, 256, 0, stream>>>(
            ru, V, b2, Q00, Q01, Q10, Q11, flag, out);
    } else {
        mono_kernel<false><<<dim3(kPts / 4 / 256, 8), 256, 0, stream>>>(
            dm, W1, b1, W2, b2, Q00, Q01, Q10, Q11, nullptr, out);
    }
}